// Round 4
// baseline (677.745 us; speedup 1.0000x reference)
//
#include <hip/hip_runtime.h>

// VectorQuantizer: z [16,1024,512] f32, emb [8192,512] f32
// out: [z_q_st (16384*512 f32)][total_loss (1 f32)][idx as f32 (16384)]
//
// bf16 MFMA computes approx dot(z,emb) (argmax acc == argmin dist); epilogue keeps
// per-(row,256-tile) max + candidates within MARGIN_A; finalize rechecks candidates
// with the EXACT fp32 d-ascending fmaf chain + q = fl(s1-2*dot) quantization
// (bit-identical to the round-2 kernel that passed absmax 0), lowest-index ties.
//
// Round 4: flatmm-style GEMM — operands are L2/L3-resident (zh 16MB + eh 8MB), and
// the pack kernels emit fragment-linear layout, so fragments are loaded DIRECTLY
// from global into registers (no LDS staging, no K-loop barriers, no vmcnt(0)
// drain). Register double-buffer one k-slot ahead; full unroll => static indices.

#define N_TOK 16384
#define DIM   512
#define NEMB  8192
#define BETA  0.25f
#define NKT   32              // 8192 / 256 n-tiles
#define MARGIN_A 2.0e-4f      // in acc(dot) units; plateau 3.05e-5 + bf16 err (14-sigma)

using short8 = __attribute__((ext_vector_type(8))) short;
using f32x4  = __attribute__((ext_vector_type(4))) float;

// ---- ws layout (bytes), total ~46.2 MB ----
#define WS_ACC  0
#define WS_CNT  64
#define WS_PMAX (WS_CNT  + N_TOK*NKT*4)
#define WS_PIDX (WS_PMAX + N_TOK*NKT*4)
#define WS_EXTK (WS_PIDX + N_TOK*NKT*4)
#define WS_S1   (WS_EXTK + N_TOK*NKT*7*4)
#define WS_ZH   (WS_S1   + N_TOK*4)
#define WS_EH   (WS_ZH   + N_TOK*DIM*2)

__device__ inline short f2bf(float f) {   // RNE float->bf16
  unsigned u = __builtin_bit_cast(unsigned, f);
  u += 0x7fffu + ((u >> 16) & 1u);
  return (short)(u >> 16);
}

// pack z -> zh bf16, layout [mt(128)][kc(64)][mi(128)][j(8)]
__global__ void vq_pack_z(const float* __restrict__ z, short* __restrict__ zh) {
  int c = blockIdx.x * 256 + threadIdx.x;           // 0..1M-1
  int mi = c & 127, kc = (c >> 7) & 63, mt = c >> 13;
  const float* src = z + (size_t)(mt * 128 + mi) * DIM + kc * 8;
  float4 f0 = *(const float4*)src, f1 = *(const float4*)(src + 4);
  short8 o;
  o[0]=f2bf(f0.x); o[1]=f2bf(f0.y); o[2]=f2bf(f0.z); o[3]=f2bf(f0.w);
  o[4]=f2bf(f1.x); o[5]=f2bf(f1.y); o[6]=f2bf(f1.z); o[7]=f2bf(f1.w);
  *(short8*)(zh + (size_t)c * 8) = o;
}

// pack emb -> eh bf16, layout [nt(32)][kc(64)][ni(256)][j(8)]
__global__ void vq_pack_e(const float* __restrict__ e, short* __restrict__ eh) {
  int c = blockIdx.x * 256 + threadIdx.x;           // 0..512K-1
  int ni = c & 255, kc = (c >> 8) & 63, nt = c >> 14;
  const float* src = e + (size_t)(nt * 256 + ni) * DIM + kc * 8;
  float4 f0 = *(const float4*)src, f1 = *(const float4*)(src + 4);
  short8 o;
  o[0]=f2bf(f0.x); o[1]=f2bf(f0.y); o[2]=f2bf(f0.z); o[3]=f2bf(f0.w);
  o[4]=f2bf(f1.x); o[5]=f2bf(f1.y); o[6]=f2bf(f1.z); o[7]=f2bf(f1.w);
  *(short8*)(eh + (size_t)c * 8) = o;
}

// s1[n] = fp32( sum_fp64( fp32(z^2) ) )  -- unchanged (passing) path
__global__ void vq_s1(const float* __restrict__ z, float* __restrict__ s1) {
  int w = threadIdx.x >> 6, lane = threadIdx.x & 63;
  int row = blockIdx.x * 4 + w;
  const float4* r = (const float4*)(z + (size_t)row * DIM);
  float4 v0 = r[lane * 2], v1 = r[lane * 2 + 1];
  float p0=v0.x*v0.x, p1=v0.y*v0.y, p2=v0.z*v0.z, p3=v0.w*v0.w;
  float p4=v1.x*v1.x, p5=v1.y*v1.y, p6=v1.z*v1.z, p7=v1.w*v1.w;
  double s = (double)p0+(double)p1+(double)p2+(double)p3
           + (double)p4+(double)p5+(double)p6+(double)p7;
  #pragma unroll
  for (int m = 32; m >= 1; m >>= 1) s += __shfl_xor(s, m);
  if (lane == 0) s1[row] = (float)s;
}

// Flatmm MFMA + fused argmax/candidate epilogue.
// Block = 128 rows x 256 cols, 4 waves (2m x 2n), wave tile 64x128.
// Fragments loaded straight from global (fragment-linear packed layout).
__global__ __launch_bounds__(256, 2)
void vq_mfma(const short* __restrict__ zh, const short* __restrict__ eh,
             float* __restrict__ pmax, int* __restrict__ pidx,
             int* __restrict__ cnt, int* __restrict__ extk) {
  __shared__ float cmbv[128][2];
  __shared__ int   cmbk[128][2];
  __shared__ float bbv[128];
  __shared__ int   bbk[128];

  const int nt = blockIdx.x, mt = blockIdx.y;
  const int n0 = nt * 256, m0 = mt * 128;
  const int tid = threadIdx.x;
  const int wid = tid >> 6, lane = tid & 63;
  const int wm = wid >> 1, wn = wid & 1;
  const int quad = lane >> 4, lc = lane & 15;

  f32x4 C[4][8];
  #pragma unroll
  for (int i = 0; i < 4; ++i)
    #pragma unroll
    for (int j = 0; j < 8; ++j) C[i][j] = (f32x4){0.f, 0.f, 0.f, 0.f};

  // short8-unit bases; fragment (k-slot t, quad) lives at kcl = t*4 + quad
  const short8* gA = (const short8*)zh + (size_t)mt * 64 * 128;
  const short8* gB = (const short8*)eh + (size_t)nt * 64 * 256;
  const int aoff = wm * 64 + lc;    // + mf*16 + kcl*128
  const int boff = wn * 128 + lc;   // + nf*16 + kcl*256

  short8 a[2][4], b[2][8];

  auto loadk = [&](int buf, int t) {
    const int kcl = t * 4 + quad;
    #pragma unroll
    for (int mf = 0; mf < 4; ++mf) a[buf][mf] = gA[(size_t)kcl * 128 + aoff + mf * 16];
    #pragma unroll
    for (int nf = 0; nf < 8; ++nf) b[buf][nf] = gB[(size_t)kcl * 256 + boff + nf * 16];
  };

  loadk(0, 0);
  #pragma unroll
  for (int t = 0; t < 16; ++t) {          // 16 k-slots of K=32 (t = step*2+ks, as before)
    const int cur = t & 1;
    if (t < 15) loadk(cur ^ 1, t + 1);    // prefetch next slot while computing
    #pragma unroll
    for (int nf = 0; nf < 8; ++nf) {
      #pragma unroll
      for (int mf = 0; mf < 4; ++mf)
        C[mf][nf] = __builtin_amdgcn_mfma_f32_16x16x32_bf16(a[cur][mf], b[cur][nf],
                                                            C[mf][nf], 0, 0, 0);
    }
  }

  // ---- epilogue: per-row argmax over this 256-wide tile + candidate emission ----
  // (unchanged from the passing round-3 kernel; acc chains are bit-identical)
  #pragma unroll
  for (int mf = 0; mf < 4; ++mf)
    #pragma unroll
    for (int r = 0; r < 4; ++r) {
      float bv = C[mf][0][r]; int bn = 0;
      #pragma unroll
      for (int nf = 1; nf < 8; ++nf) {
        float v = C[mf][nf][r];
        if (v > bv) { bv = v; bn = nf; }      // strict >: ties -> lowest nf
      }
      int bk = n0 + wn * 128 + bn * 16 + lc;
      #pragma unroll
      for (int m = 8; m >= 1; m >>= 1) {       // reduce 16 lanes (same quad)
        float vo = __shfl_xor(bv, m); int ko = __shfl_xor(bk, m);
        if (vo > bv || (vo == bv && ko < bk)) { bv = vo; bk = ko; }
      }
      if (lc == 0) {
        int row = wm * 64 + mf * 16 + quad * 4 + r;
        cmbv[row][wn] = bv; cmbk[row][wn] = bk;
      }
    }
  __syncthreads();
  if (tid < 128) {
    float v0 = cmbv[tid][0], v1 = cmbv[tid][1];
    int k0i = cmbk[tid][0], k1i = cmbk[tid][1];
    float bv; int bk;
    if (v1 > v0 || (v1 == v0 && k1i < k0i)) { bv = v1; bk = k1i; }
    else                                    { bv = v0; bk = k0i; }
    bbv[tid] = bv; bbk[tid] = bk;
    size_t rg = (size_t)(m0 + tid) * NKT + nt;
    pmax[rg] = bv; pidx[rg] = bk;
  }
  __syncthreads();
  // emit near-max extras
  #pragma unroll
  for (int mf = 0; mf < 4; ++mf)
    #pragma unroll
    for (int nf = 0; nf < 8; ++nf)
      #pragma unroll
      for (int r = 0; r < 4; ++r) {
        int row = wm * 64 + mf * 16 + quad * 4 + r;
        float v = C[mf][nf][r];
        if (v >= bbv[row] - MARGIN_A) {
          int k = n0 + wn * 128 + nf * 16 + lc;
          if (k != bbk[row]) {
            size_t rg = (size_t)(m0 + row) * NKT + nt;
            int slot = atomicAdd(&cnt[rg], 1);
            if (slot < 7) extk[rg * 7 + slot] = k;
          }
        }
      }
}

// per-row: pick candidate tiles, EXACT fp32 recheck, gather/outputs/loss (unchanged)
__global__ void vq_finalize(const float* __restrict__ z, const float* __restrict__ emb,
                            const float* __restrict__ s1g,
                            const float* __restrict__ pmax, const int* __restrict__ pidx,
                            const int* __restrict__ cnt, const int* __restrict__ extk,
                            float* __restrict__ out, double* __restrict__ acc) {
  __shared__ int candk[4][40];
  __shared__ int lcnt[4];
  const int w = threadIdx.x >> 6, l = threadIdx.x & 63;
  const int row = blockIdx.x * 4 + w;
  const int l5 = l & 31;
  if (l == 0) lcnt[w] = 0;
  __syncthreads();
  const size_t rb = (size_t)row * NKT;
  float pv = pmax[rb + l5]; int pk = pidx[rb + l5];
  float gv = pv; int gk = pk;
  #pragma unroll
  for (int m = 16; m >= 1; m >>= 1) {
    float vo = __shfl_xor(gv, m); int ko = __shfl_xor(gk, m);
    if (vo > gv || (vo == gv && ko < gk)) { gv = vo; gk = ko; }
  }
  if (l < 32 && pv >= gv - MARGIN_A) {
    int c = cnt[rb + l5]; if (c > 7) c = 7;
    int slot = atomicAdd(&lcnt[w], 1 + c);
    if (slot < 40) candk[w][slot] = pk;
    for (int i = 0; i < c; ++i)
      if (slot + 1 + i < 40) candk[w][slot + 1 + i] = extk[(rb + l5) * 7 + i];
  }
  __syncthreads();
  int Cc = lcnt[w]; if (Cc > 40) Cc = 40;
  float qb = 1e30f; int kb = 0x7fffffff;
  const float s1 = s1g[row];
  const float* zr = z + (size_t)row * DIM;
  for (int ci = l5; ci < Cc; ci += 32) {    // lanes 32-63 duplicate (harmless)
    int k = candk[w][ci];
    const float* er = emb + (size_t)k * DIM;
    float d = 0.f;
    for (int i = 0; i < DIM; ++i) d = fmaf(zr[i], er[i], d);  // strict d-ascending
    float q = s1 - 2.f * d;                  // single-rounding quantize (2*d exact)
    if (q < qb || (q == qb && k < kb)) { qb = q; kb = k; }
  }
  #pragma unroll
  for (int m = 32; m >= 1; m >>= 1) {
    float qo = __shfl_xor(qb, m); int ko = __shfl_xor(kb, m);
    if (qo < qb || (qo == qb && ko < kb)) { qb = qo; kb = ko; }
  }
  const float4* zr4 = (const float4*)zr;
  const float4* qr4 = (const float4*)(emb + (size_t)kb * DIM);
  float4 zv0 = zr4[l * 2], zv1 = zr4[l * 2 + 1];
  float4 qv0 = qr4[l * 2], qv1 = qr4[l * 2 + 1];
  float ls = 0.f; float4 ov0, ov1;
  {
    const float* zp=(const float*)&zv0; const float* qp=(const float*)&qv0; float* op=(float*)&ov0;
    #pragma unroll
    for (int e = 0; e < 4; ++e) { float d = qp[e]-zp[e]; op[e] = zp[e]+d; ls += d*d; }
  }
  {
    const float* zp=(const float*)&zv1; const float* qp=(const float*)&qv1; float* op=(float*)&ov1;
    #pragma unroll
    for (int e = 0; e < 4; ++e) { float d = qp[e]-zp[e]; op[e] = zp[e]+d; ls += d*d; }
  }
  float4* orow = (float4*)(out + (size_t)row * DIM);
  orow[l * 2] = ov0; orow[l * 2 + 1] = ov1;
  #pragma unroll
  for (int m = 32; m >= 1; m >>= 1) ls += __shfl_xor(ls, m);
  if (l == 0) {
    out[(size_t)N_TOK * DIM + 1 + row] = (float)kb;
    atomicAdd(acc, (double)ls);
  }
}

__global__ void vq_loss(const double* __restrict__ acc, float* __restrict__ out) {
  out[(size_t)N_TOK * DIM] =
      (float)(*acc * (1.0 + (double)BETA) / ((double)N_TOK * (double)DIM));
}

extern "C" void kernel_launch(void* const* d_in, const int* in_sizes, int n_in,
                              void* d_out, int out_size, void* d_ws, size_t ws_size,
                              hipStream_t stream) {
  const float* z   = (const float*)d_in[0];
  const float* emb = (const float*)d_in[1];
  float* out = (float*)d_out;
  char* ws = (char*)d_ws;
  double* acc  = (double*)(ws + WS_ACC);
  int*    cnt  = (int*)(ws + WS_CNT);
  float*  pmax = (float*)(ws + WS_PMAX);
  int*    pidx = (int*)(ws + WS_PIDX);
  int*    extk = (int*)(ws + WS_EXTK);
  float*  s1   = (float*)(ws + WS_S1);
  short*  zh   = (short*)(ws + WS_ZH);
  short*  eh   = (short*)(ws + WS_EH);

  hipMemsetAsync(ws, 0, WS_CNT + (size_t)N_TOK * NKT * 4, stream);  // acc + cnt
  vq_pack_z<<<N_TOK * DIM / 8 / 256, 256, 0, stream>>>(z, zh);
  vq_pack_e<<<NEMB * DIM / 8 / 256, 256, 0, stream>>>(emb, eh);
  vq_s1<<<N_TOK / 4, 256, 0, stream>>>(z, s1);
  vq_mfma<<<dim3(NEMB / 256, N_TOK / 128), 256, 0, stream>>>(zh, eh, pmax, pidx, cnt, extk);
  vq_finalize<<<N_TOK / 4, 256, 0, stream>>>(z, emb, s1, pmax, pidx, cnt, extk, out, acc);
  vq_loss<<<1, 1, 0, stream>>>(acc, out);
}

// Round 5
// 586.696 us; speedup vs baseline: 1.1552x; 1.1552x over previous
//
#include <hip/hip_runtime.h>

// VectorQuantizer: z [16,1024,512] f32, emb [8192,512] f32
// out: [z_q_st (16384*512 f32)][total_loss (1 f32)][idx as f32 (16384)]
//
// bf16 MFMA computes approx dot(z,emb) (argmax acc == argmin dist); epilogue keeps
// per-(row,256-tile) max + candidates within MARGIN_A; finalize rechecks candidates
// with the EXACT fp32 d-ascending fmaf chain + q = fl(s1-2*dot) quantization
// (bit-identical to the round-2 kernel that passed absmax 0), lowest-index ties.
//
// Round 5: 256x256 tile, 8 waves, double-buffered LDS (128KB), 2-phase schedule
// (issue next-step global_load_lds BEFORE computing current step; one
// vmcnt(0)+barrier per step via __syncthreads). Pack kernels are wave-per-row
// (coalesced reads, 16B scattered writes) with s1 fused into pack_z.

#define N_TOK 16384
#define DIM   512
#define NEMB  8192
#define BETA  0.25f
#define NKT   32              // 8192 / 256 n-tiles
#define MARGIN_A 2.0e-4f      // in acc(dot) units; plateau 3.05e-5 + bf16 err (14-sigma)

using short8 = __attribute__((ext_vector_type(8))) short;
using f32x4  = __attribute__((ext_vector_type(4))) float;

// ---- ws layout (bytes), total ~46.2 MB ----
#define WS_ACC  0
#define WS_CNT  64
#define WS_PMAX (WS_CNT  + N_TOK*NKT*4)
#define WS_PIDX (WS_PMAX + N_TOK*NKT*4)
#define WS_EXTK (WS_PIDX + N_TOK*NKT*4)
#define WS_S1   (WS_EXTK + N_TOK*NKT*7*4)
#define WS_ZH   (WS_S1   + N_TOK*4)
#define WS_EH   (WS_ZH   + N_TOK*DIM*2)

__device__ inline short f2bf(float f) {   // RNE float->bf16
  unsigned u = __builtin_bit_cast(unsigned, f);
  u += 0x7fffu + ((u >> 16) & 1u);
  return (short)(u >> 16);
}

#define GLDS16(g, l) __builtin_amdgcn_global_load_lds( \
    (const __attribute__((address_space(1))) void*)(g), \
    (__attribute__((address_space(3))) void*)(l), 16, 0, 0)

// pack z -> zh bf16 fragment layout [mt(64)][kc(64)][mi(256)][j(8)], fused s1.
// Wave-per-row: coalesced 2KB row read; scattered 16B fragment writes.
__global__ void vq_pack_z(const float* __restrict__ z, short* __restrict__ zh,
                          float* __restrict__ s1) {
  const int w = threadIdx.x >> 6, lane = threadIdx.x & 63;
  const int row = blockIdx.x * 4 + w;
  const float4* r = (const float4*)(z + (size_t)row * DIM);
  float4 v0 = r[lane * 2], v1 = r[lane * 2 + 1];
  // s1: bit-identical to the passing round-2 path (same products, order, reduce)
  float p0=v0.x*v0.x, p1=v0.y*v0.y, p2=v0.z*v0.z, p3=v0.w*v0.w;
  float p4=v1.x*v1.x, p5=v1.y*v1.y, p6=v1.z*v1.z, p7=v1.w*v1.w;
  double s = (double)p0+(double)p1+(double)p2+(double)p3
           + (double)p4+(double)p5+(double)p6+(double)p7;
  #pragma unroll
  for (int m = 32; m >= 1; m >>= 1) s += __shfl_xor(s, m);
  if (lane == 0) s1[row] = (float)s;
  short8 o;
  o[0]=f2bf(v0.x); o[1]=f2bf(v0.y); o[2]=f2bf(v0.z); o[3]=f2bf(v0.w);
  o[4]=f2bf(v1.x); o[5]=f2bf(v1.y); o[6]=f2bf(v1.z); o[7]=f2bf(v1.w);
  const int mt = row >> 8, mi = row & 255;          // kc == lane
  *(short8*)(zh + ((((size_t)mt * 64 + lane) * 256) + mi) * 8) = o;
}

// pack emb -> eh bf16 fragment layout [nt(32)][kc(64)][ni(256)][j(8)], wave-per-row.
__global__ void vq_pack_e(const float* __restrict__ e, short* __restrict__ eh) {
  const int w = threadIdx.x >> 6, lane = threadIdx.x & 63;
  const int row = blockIdx.x * 4 + w;
  const float4* r = (const float4*)(e + (size_t)row * DIM);
  float4 v0 = r[lane * 2], v1 = r[lane * 2 + 1];
  short8 o;
  o[0]=f2bf(v0.x); o[1]=f2bf(v0.y); o[2]=f2bf(v0.z); o[3]=f2bf(v0.w);
  o[4]=f2bf(v1.x); o[5]=f2bf(v1.y); o[6]=f2bf(v1.z); o[7]=f2bf(v1.w);
  const int nt = row >> 8, ni = row & 255;
  *(short8*)(eh + ((((size_t)nt * 64 + lane) * 256) + ni) * 8) = o;
}

// MFMA GEMM + fused argmax/candidate epilogue.
// Block = 256 rows x 256 cols, 8 waves (2m x 4n), wave tile 128x64, BK=64, dbuf LDS.
__global__ __launch_bounds__(512, 2)
void vq_mfma(const short* __restrict__ zh, const short* __restrict__ eh,
             float* __restrict__ pmax, int* __restrict__ pidx,
             int* __restrict__ cnt, int* __restrict__ extk) {
  __shared__ short8 lA[2][2048];   // [buf][kc(8)][mi(256)] : 32KB each
  __shared__ short8 lB[2][2048];   // [buf][kc(8)][ni(256)] : 32KB each

  const int nt = blockIdx.x, mt = blockIdx.y;
  const int n0 = nt * 256, m0 = mt * 256;
  const int tid = threadIdx.x;
  const int wid = tid >> 6, lane = tid & 63;
  const int wm = wid >> 2, wn = wid & 3;
  const int quad = lane >> 4, lc = lane & 15;

  f32x4 C[8][4];
  #pragma unroll
  for (int i = 0; i < 8; ++i)
    #pragma unroll
    for (int j = 0; j < 4; ++j) C[i][j] = (f32x4){0.f, 0.f, 0.f, 0.f};

  const char* gA = (const char*)zh + (size_t)mt * 16384 * 16;  // 64*256 short8 per mt
  const char* gB = (const char*)eh + (size_t)nt * 16384 * 16;

  auto stage = [&](int buf, int t) {
    const char* a = gA + (size_t)t * 32768;   // step t: kc [8t,8t+8) contiguous 32KB
    const char* b = gB + (size_t)t * 32768;
    #pragma unroll
    for (int i = 0; i < 4; ++i) {
      const int c = wid * 4 + i;              // 32 chunks of 1KB per operand
      GLDS16(a + c * 1024 + lane * 16, (char*)&lA[buf][0] + c * 1024);
      GLDS16(b + c * 1024 + lane * 16, (char*)&lB[buf][0] + c * 1024);
    }
  };

  stage(0, 0);
  __syncthreads();                             // vmcnt(0)+barrier (compiler-emitted)
  #pragma unroll
  for (int t = 0; t < 8; ++t) {
    const int cur = t & 1;
    if (t < 7) stage(cur ^ 1, t + 1);          // issue next-step loads BEFORE compute
    #pragma unroll
    for (int s = 0; s < 2; ++s) {              // two K=32 slots per BK=64 step
      const int kx = s * 4 + quad;
      short8 a[8], b[4];
      #pragma unroll
      for (int mf = 0; mf < 8; ++mf) a[mf] = lA[cur][kx * 256 + wm * 128 + mf * 16 + lc];
      #pragma unroll
      for (int nf = 0; nf < 4; ++nf) b[nf] = lB[cur][kx * 256 + wn * 64 + nf * 16 + lc];
      #pragma unroll
      for (int mf = 0; mf < 8; ++mf)
        #pragma unroll
        for (int nf = 0; nf < 4; ++nf)
          C[mf][nf] = __builtin_amdgcn_mfma_f32_16x16x32_bf16(a[mf], b[nf],
                                                              C[mf][nf], 0, 0, 0);
    }
    __syncthreads();                           // drains staged loads + sync readers
  }

  // ---- epilogue (aliases lA[0]; K-loop fully done after final barrier) ----
  float* cmbv = (float*)&lA[0][0];             // [256][4]
  int*   cmbk = (int*)(cmbv + 1024);
  float* bbv  = (float*)(cmbk + 1024);
  int*   bbk  = (int*)(bbv + 256);

  // per-row argmax over this 256-wide tile; C/D layout: row=quad*4+rr, col=lc
  #pragma unroll
  for (int mf = 0; mf < 8; ++mf)
    #pragma unroll
    for (int rr = 0; rr < 4; ++rr) {
      float bv = C[mf][0][rr]; int bn = 0;
      #pragma unroll
      for (int nf = 1; nf < 4; ++nf) {
        float v = C[mf][nf][rr];
        if (v > bv) { bv = v; bn = nf; }       // strict >: ties -> lowest nf (lowest k)
      }
      int bk = n0 + wn * 64 + bn * 16 + lc;
      #pragma unroll
      for (int m = 8; m >= 1; m >>= 1) {       // reduce 16 lanes (same quad)
        float vo = __shfl_xor(bv, m); int ko = __shfl_xor(bk, m);
        if (vo > bv || (vo == bv && ko < bk)) { bv = vo; bk = ko; }
      }
      if (lc == 0) {
        int row = wm * 128 + mf * 16 + quad * 4 + rr;
        cmbv[row * 4 + wn] = bv; cmbk[row * 4 + wn] = bk;
      }
    }
  __syncthreads();
  if (tid < 256) {
    float bv = cmbv[tid * 4 + 0]; int bk = cmbk[tid * 4 + 0];
    #pragma unroll
    for (int q = 1; q < 4; ++q) {              // ascending wn => ascending k: strict >
      float v = cmbv[tid * 4 + q]; int k = cmbk[tid * 4 + q];
      if (v > bv) { bv = v; bk = k; }
    }
    bbv[tid] = bv; bbk[tid] = bk;
    size_t rg = (size_t)(m0 + tid) * NKT + nt;
    pmax[rg] = bv; pidx[rg] = bk;
  }
  __syncthreads();
  // emit near-max extras
  #pragma unroll
  for (int mf = 0; mf < 8; ++mf)
    #pragma unroll
    for (int nf = 0; nf < 4; ++nf)
      #pragma unroll
      for (int rr = 0; rr < 4; ++rr) {
        int row = wm * 128 + mf * 16 + quad * 4 + rr;
        float v = C[mf][nf][rr];
        if (v >= bbv[row] - MARGIN_A) {
          int k = n0 + wn * 64 + nf * 16 + lc;
          if (k != bbk[row]) {
            size_t rg = (size_t)(m0 + row) * NKT + nt;
            int slot = atomicAdd(&cnt[rg], 1);
            if (slot < 7) extk[rg * 7 + slot] = k;
          }
        }
      }
}

// per-row: pick candidate tiles, EXACT fp32 recheck, gather/outputs/loss (unchanged)
__global__ void vq_finalize(const float* __restrict__ z, const float* __restrict__ emb,
                            const float* __restrict__ s1g,
                            const float* __restrict__ pmax, const int* __restrict__ pidx,
                            const int* __restrict__ cnt, const int* __restrict__ extk,
                            float* __restrict__ out, double* __restrict__ acc) {
  __shared__ int candk[4][40];
  __shared__ int lcnt[4];
  const int w = threadIdx.x >> 6, l = threadIdx.x & 63;
  const int row = blockIdx.x * 4 + w;
  const int l5 = l & 31;
  if (l == 0) lcnt[w] = 0;
  __syncthreads();
  const size_t rb = (size_t)row * NKT;
  float pv = pmax[rb + l5]; int pk = pidx[rb + l5];
  float gv = pv; int gk = pk;
  #pragma unroll
  for (int m = 16; m >= 1; m >>= 1) {
    float vo = __shfl_xor(gv, m); int ko = __shfl_xor(gk, m);
    if (vo > gv || (vo == gv && ko < gk)) { gv = vo; gk = ko; }
  }
  if (l < 32 && pv >= gv - MARGIN_A) {
    int c = cnt[rb + l5]; if (c > 7) c = 7;
    int slot = atomicAdd(&lcnt[w], 1 + c);
    if (slot < 40) candk[w][slot] = pk;
    for (int i = 0; i < c; ++i)
      if (slot + 1 + i < 40) candk[w][slot + 1 + i] = extk[(rb + l5) * 7 + i];
  }
  __syncthreads();
  int Cc = lcnt[w]; if (Cc > 40) Cc = 40;
  float qb = 1e30f; int kb = 0x7fffffff;
  const float s1 = s1g[row];
  const float* zr = z + (size_t)row * DIM;
  for (int ci = l5; ci < Cc; ci += 32) {    // lanes 32-63 duplicate (harmless)
    int k = candk[w][ci];
    const float* er = emb + (size_t)k * DIM;
    float d = 0.f;
    for (int i = 0; i < DIM; ++i) d = fmaf(zr[i], er[i], d);  // strict d-ascending
    float q = s1 - 2.f * d;                  // single-rounding quantize (2*d exact)
    if (q < qb || (q == qb && k < kb)) { qb = q; kb = k; }
  }
  #pragma unroll
  for (int m = 32; m >= 1; m >>= 1) {
    float qo = __shfl_xor(qb, m); int ko = __shfl_xor(kb, m);
    if (qo < qb || (qo == qb && ko < kb)) { qb = qo; kb = ko; }
  }
  const float4* zr4 = (const float4*)zr;
  const float4* qr4 = (const float4*)(emb + (size_t)kb * DIM);
  float4 zv0 = zr4[l * 2], zv1 = zr4[l * 2 + 1];
  float4 qv0 = qr4[l * 2], qv1 = qr4[l * 2 + 1];
  float ls = 0.f; float4 ov0, ov1;
  {
    const float* zp=(const float*)&zv0; const float* qp=(const float*)&qv0; float* op=(float*)&ov0;
    #pragma unroll
    for (int e = 0; e < 4; ++e) { float d = qp[e]-zp[e]; op[e] = zp[e]+d; ls += d*d; }
  }
  {
    const float* zp=(const float*)&zv1; const float* qp=(const float*)&qv1; float* op=(float*)&ov1;
    #pragma unroll
    for (int e = 0; e < 4; ++e) { float d = qp[e]-zp[e]; op[e] = zp[e]+d; ls += d*d; }
  }
  float4* orow = (float4*)(out + (size_t)row * DIM);
  orow[l * 2] = ov0; orow[l * 2 + 1] = ov1;
  #pragma unroll
  for (int m = 32; m >= 1; m >>= 1) ls += __shfl_xor(ls, m);
  if (l == 0) {
    out[(size_t)N_TOK * DIM + 1 + row] = (float)kb;
    atomicAdd(acc, (double)ls);
  }
}

__global__ void vq_loss(const double* __restrict__ acc, float* __restrict__ out) {
  out[(size_t)N_TOK * DIM] =
      (float)(*acc * (1.0 + (double)BETA) / ((double)N_TOK * (double)DIM));
}

extern "C" void kernel_launch(void* const* d_in, const int* in_sizes, int n_in,
                              void* d_out, int out_size, void* d_ws, size_t ws_size,
                              hipStream_t stream) {
  const float* z   = (const float*)d_in[0];
  const float* emb = (const float*)d_in[1];
  float* out = (float*)d_out;
  char* ws = (char*)d_ws;
  double* acc  = (double*)(ws + WS_ACC);
  int*    cnt  = (int*)(ws + WS_CNT);
  float*  pmax = (float*)(ws + WS_PMAX);
  int*    pidx = (int*)(ws + WS_PIDX);
  int*    extk = (int*)(ws + WS_EXTK);
  float*  s1   = (float*)(ws + WS_S1);
  short*  zh   = (short*)(ws + WS_ZH);
  short*  eh   = (short*)(ws + WS_EH);

  hipMemsetAsync(ws, 0, WS_CNT + (size_t)N_TOK * NKT * 4, stream);  // acc + cnt
  vq_pack_z<<<N_TOK / 4, 256, 0, stream>>>(z, zh, s1);
  vq_pack_e<<<NEMB / 4, 256, 0, stream>>>(emb, eh);
  vq_mfma<<<dim3(NEMB / 256, N_TOK / 256), 512, 0, stream>>>(zh, eh, pmax, pidx, cnt, extk);
  vq_finalize<<<N_TOK / 4, 256, 0, stream>>>(z, emb, s1, pmax, pidx, cnt, extk, out, acc);
  vq_loss<<<1, 1, 0, stream>>>(acc, out);
}

// Round 6
// 573.550 us; speedup vs baseline: 1.1817x; 1.0229x over previous
//
#include <hip/hip_runtime.h>

// VectorQuantizer: z [16,1024,512] f32, emb [8192,512] f32
// out: [z_q_st (16384*512 f32)][total_loss (1 f32)][idx as f32 (16384)]
//
// bf16 MFMA computes approx dot(z,emb) (argmax acc == argmin dist); epilogue keeps
// per-(row,256-tile) max + candidates within MARGIN_A; finalize rechecks candidates
// with the EXACT fp32 d-ascending fmaf chain + q = fl(s1-2*dot) quantization
// (bit-identical to the round-2 kernel that passed absmax 0), lowest-index ties.
//
// Round 6: same 256x256 / 8-wave / dbuf-LDS GEMM as round 5, but T4 counted-vmcnt
// schedule: s_waitcnt vmcnt(8) + raw s_barrier instead of __syncthreads()'s
// vmcnt(0) drain. Next-step loads stay in flight across both barriers. T5
// setprio(1) around the MFMA cluster (phase-split now gives it role diversity).

#define N_TOK 16384
#define DIM   512
#define NEMB  8192
#define BETA  0.25f
#define NKT   32              // 8192 / 256 n-tiles
#define MARGIN_A 2.0e-4f      // in acc(dot) units; plateau 3.05e-5 + bf16 err (14-sigma)

using short8 = __attribute__((ext_vector_type(8))) short;
using f32x4  = __attribute__((ext_vector_type(4))) float;

// ---- ws layout (bytes), total ~46.2 MB ----
#define WS_ACC  0
#define WS_CNT  64
#define WS_PMAX (WS_CNT  + N_TOK*NKT*4)
#define WS_PIDX (WS_PMAX + N_TOK*NKT*4)
#define WS_EXTK (WS_PIDX + N_TOK*NKT*4)
#define WS_S1   (WS_EXTK + N_TOK*NKT*7*4)
#define WS_ZH   (WS_S1   + N_TOK*4)
#define WS_EH   (WS_ZH   + N_TOK*DIM*2)

__device__ inline short f2bf(float f) {   // RNE float->bf16
  unsigned u = __builtin_bit_cast(unsigned, f);
  u += 0x7fffu + ((u >> 16) & 1u);
  return (short)(u >> 16);
}

#define GLDS16(g, l) __builtin_amdgcn_global_load_lds( \
    (const __attribute__((address_space(1))) void*)(g), \
    (__attribute__((address_space(3))) void*)(l), 16, 0, 0)

// pack z -> zh bf16 fragment layout [mt(64)][kc(64)][mi(256)][j(8)], fused s1.
__global__ void vq_pack_z(const float* __restrict__ z, short* __restrict__ zh,
                          float* __restrict__ s1) {
  const int w = threadIdx.x >> 6, lane = threadIdx.x & 63;
  const int row = blockIdx.x * 4 + w;
  const float4* r = (const float4*)(z + (size_t)row * DIM);
  float4 v0 = r[lane * 2], v1 = r[lane * 2 + 1];
  // s1: bit-identical to the passing round-2 path (same products, order, reduce)
  float p0=v0.x*v0.x, p1=v0.y*v0.y, p2=v0.z*v0.z, p3=v0.w*v0.w;
  float p4=v1.x*v1.x, p5=v1.y*v1.y, p6=v1.z*v1.z, p7=v1.w*v1.w;
  double s = (double)p0+(double)p1+(double)p2+(double)p3
           + (double)p4+(double)p5+(double)p6+(double)p7;
  #pragma unroll
  for (int m = 32; m >= 1; m >>= 1) s += __shfl_xor(s, m);
  if (lane == 0) s1[row] = (float)s;
  short8 o;
  o[0]=f2bf(v0.x); o[1]=f2bf(v0.y); o[2]=f2bf(v0.z); o[3]=f2bf(v0.w);
  o[4]=f2bf(v1.x); o[5]=f2bf(v1.y); o[6]=f2bf(v1.z); o[7]=f2bf(v1.w);
  const int mt = row >> 8, mi = row & 255;          // kc == lane
  *(short8*)(zh + ((((size_t)mt * 64 + lane) * 256) + mi) * 8) = o;
}

// pack emb -> eh bf16 fragment layout [nt(32)][kc(64)][ni(256)][j(8)], wave-per-row.
__global__ void vq_pack_e(const float* __restrict__ e, short* __restrict__ eh) {
  const int w = threadIdx.x >> 6, lane = threadIdx.x & 63;
  const int row = blockIdx.x * 4 + w;
  const float4* r = (const float4*)(e + (size_t)row * DIM);
  float4 v0 = r[lane * 2], v1 = r[lane * 2 + 1];
  short8 o;
  o[0]=f2bf(v0.x); o[1]=f2bf(v0.y); o[2]=f2bf(v0.z); o[3]=f2bf(v0.w);
  o[4]=f2bf(v1.x); o[5]=f2bf(v1.y); o[6]=f2bf(v1.z); o[7]=f2bf(v1.w);
  const int nt = row >> 8, ni = row & 255;
  *(short8*)(eh + ((((size_t)nt * 64 + lane) * 256) + ni) * 8) = o;
}

// MFMA GEMM + fused argmax/candidate epilogue.
// Block = 256 rows x 256 cols, 8 waves (2m x 4n), wave tile 128x64, BK=64, dbuf LDS.
__global__ __launch_bounds__(512, 2)
void vq_mfma(const short* __restrict__ zh, const short* __restrict__ eh,
             float* __restrict__ pmax, int* __restrict__ pidx,
             int* __restrict__ cnt, int* __restrict__ extk) {
  __shared__ short8 lA[2][2048];   // [buf][kc(8)][mi(256)] : 32KB each
  __shared__ short8 lB[2][2048];   // [buf][kc(8)][ni(256)] : 32KB each

  const int nt = blockIdx.x, mt = blockIdx.y;
  const int n0 = nt * 256, m0 = mt * 256;
  const int tid = threadIdx.x;
  const int wid = tid >> 6, lane = tid & 63;
  const int wm = wid >> 2, wn = wid & 3;
  const int quad = lane >> 4, lc = lane & 15;

  f32x4 C[8][4];
  #pragma unroll
  for (int i = 0; i < 8; ++i)
    #pragma unroll
    for (int j = 0; j < 4; ++j) C[i][j] = (f32x4){0.f, 0.f, 0.f, 0.f};

  const char* gA = (const char*)zh + (size_t)mt * 16384 * 16;  // 64*256 short8 per mt
  const char* gB = (const char*)eh + (size_t)nt * 16384 * 16;

  auto stage = [&](int buf, int t) {
    const char* a = gA + (size_t)t * 32768;   // step t: kc [8t,8t+8) contiguous 32KB
    const char* b = gB + (size_t)t * 32768;
    #pragma unroll
    for (int i = 0; i < 4; ++i) {
      const int c = wid * 4 + i;              // 32 chunks of 1KB per operand
      GLDS16(a + c * 1024 + lane * 16, (char*)&lA[buf][0] + c * 1024);
      GLDS16(b + c * 1024 + lane * 16, (char*)&lB[buf][0] + c * 1024);
    }
  };

  stage(0, 0);                                 // prologue: 8 loads/wave in flight
  #pragma unroll
  for (int t = 0; t < 8; ++t) {
    const int cur = t & 1;
    if (t < 7) {
      stage(cur ^ 1, t + 1);                   // issue next-step loads (8/wave)
      // wait only the PREVIOUS stage's 8 loads; this step's 8 stay in flight
      asm volatile("s_waitcnt vmcnt(8)" ::: "memory");
    } else {
      asm volatile("s_waitcnt vmcnt(0)" ::: "memory");
    }
    __builtin_amdgcn_s_barrier();              // buffer 'cur' full for all waves
    #pragma unroll
    for (int s = 0; s < 2; ++s) {              // two K=32 slots per BK=64 step
      const int kx = s * 4 + quad;
      short8 a[8], b[4];
      #pragma unroll
      for (int mf = 0; mf < 8; ++mf) a[mf] = lA[cur][kx * 256 + wm * 128 + mf * 16 + lc];
      #pragma unroll
      for (int nf = 0; nf < 4; ++nf) b[nf] = lB[cur][kx * 256 + wn * 64 + nf * 16 + lc];
      __builtin_amdgcn_s_setprio(1);
      #pragma unroll
      for (int mf = 0; mf < 8; ++mf)
        #pragma unroll
        for (int nf = 0; nf < 4; ++nf)
          C[mf][nf] = __builtin_amdgcn_mfma_f32_16x16x32_bf16(a[mf], b[nf],
                                                              C[mf][nf], 0, 0, 0);
      __builtin_amdgcn_s_setprio(0);
    }
    __builtin_amdgcn_s_barrier();              // readers done before next overwrite
  }

  // ---- epilogue (aliases lA[0]; K-loop fully done after final barrier) ----
  float* cmbv = (float*)&lA[0][0];             // [256][4]
  int*   cmbk = (int*)(cmbv + 1024);
  float* bbv  = (float*)(cmbk + 1024);
  int*   bbk  = (int*)(bbv + 256);

  // per-row argmax over this 256-wide tile; C/D layout: row=quad*4+rr, col=lc
  #pragma unroll
  for (int mf = 0; mf < 8; ++mf)
    #pragma unroll
    for (int rr = 0; rr < 4; ++rr) {
      float bv = C[mf][0][rr]; int bn = 0;
      #pragma unroll
      for (int nf = 1; nf < 4; ++nf) {
        float v = C[mf][nf][rr];
        if (v > bv) { bv = v; bn = nf; }       // strict >: ties -> lowest nf (lowest k)
      }
      int bk = n0 + wn * 64 + bn * 16 + lc;
      #pragma unroll
      for (int m = 8; m >= 1; m >>= 1) {       // reduce 16 lanes (same quad)
        float vo = __shfl_xor(bv, m); int ko = __shfl_xor(bk, m);
        if (vo > bv || (vo == bv && ko < bk)) { bv = vo; bk = ko; }
      }
      if (lc == 0) {
        int row = wm * 128 + mf * 16 + quad * 4 + rr;
        cmbv[row * 4 + wn] = bv; cmbk[row * 4 + wn] = bk;
      }
    }
  __syncthreads();
  if (tid < 256) {
    float bv = cmbv[tid * 4 + 0]; int bk = cmbk[tid * 4 + 0];
    #pragma unroll
    for (int q = 1; q < 4; ++q) {              // ascending wn => ascending k: strict >
      float v = cmbv[tid * 4 + q]; int k = cmbk[tid * 4 + q];
      if (v > bv) { bv = v; bk = k; }
    }
    bbv[tid] = bv; bbk[tid] = bk;
    size_t rg = (size_t)(m0 + tid) * NKT + nt;
    pmax[rg] = bv; pidx[rg] = bk;
  }
  __syncthreads();
  // emit near-max extras
  #pragma unroll
  for (int mf = 0; mf < 8; ++mf)
    #pragma unroll
    for (int nf = 0; nf < 4; ++nf)
      #pragma unroll
      for (int rr = 0; rr < 4; ++rr) {
        int row = wm * 128 + mf * 16 + quad * 4 + rr;
        float v = C[mf][nf][rr];
        if (v >= bbv[row] - MARGIN_A) {
          int k = n0 + wn * 64 + nf * 16 + lc;
          if (k != bbk[row]) {
            size_t rg = (size_t)(m0 + row) * NKT + nt;
            int slot = atomicAdd(&cnt[rg], 1);
            if (slot < 7) extk[rg * 7 + slot] = k;
          }
        }
      }
}

// per-row: pick candidate tiles, EXACT fp32 recheck, gather/outputs/loss (unchanged)
__global__ void vq_finalize(const float* __restrict__ z, const float* __restrict__ emb,
                            const float* __restrict__ s1g,
                            const float* __restrict__ pmax, const int* __restrict__ pidx,
                            const int* __restrict__ cnt, const int* __restrict__ extk,
                            float* __restrict__ out, double* __restrict__ acc) {
  __shared__ int candk[4][40];
  __shared__ int lcnt[4];
  const int w = threadIdx.x >> 6, l = threadIdx.x & 63;
  const int row = blockIdx.x * 4 + w;
  const int l5 = l & 31;
  if (l == 0) lcnt[w] = 0;
  __syncthreads();
  const size_t rb = (size_t)row * NKT;
  float pv = pmax[rb + l5]; int pk = pidx[rb + l5];
  float gv = pv; int gk = pk;
  #pragma unroll
  for (int m = 16; m >= 1; m >>= 1) {
    float vo = __shfl_xor(gv, m); int ko = __shfl_xor(gk, m);
    if (vo > gv || (vo == gv && ko < gk)) { gv = vo; gk = ko; }
  }
  if (l < 32 && pv >= gv - MARGIN_A) {
    int c = cnt[rb + l5]; if (c > 7) c = 7;
    int slot = atomicAdd(&lcnt[w], 1 + c);
    if (slot < 40) candk[w][slot] = pk;
    for (int i = 0; i < c; ++i)
      if (slot + 1 + i < 40) candk[w][slot + 1 + i] = extk[(rb + l5) * 7 + i];
  }
  __syncthreads();
  int Cc = lcnt[w]; if (Cc > 40) Cc = 40;
  float qb = 1e30f; int kb = 0x7fffffff;
  const float s1 = s1g[row];
  const float* zr = z + (size_t)row * DIM;
  for (int ci = l5; ci < Cc; ci += 32) {    // lanes 32-63 duplicate (harmless)
    int k = candk[w][ci];
    const float* er = emb + (size_t)k * DIM;
    float d = 0.f;
    for (int i = 0; i < DIM; ++i) d = fmaf(zr[i], er[i], d);  // strict d-ascending
    float q = s1 - 2.f * d;                  // single-rounding quantize (2*d exact)
    if (q < qb || (q == qb && k < kb)) { qb = q; kb = k; }
  }
  #pragma unroll
  for (int m = 32; m >= 1; m >>= 1) {
    float qo = __shfl_xor(qb, m); int ko = __shfl_xor(kb, m);
    if (qo < qb || (qo == qb && ko < kb)) { qb = qo; kb = ko; }
  }
  const float4* zr4 = (const float4*)zr;
  const float4* qr4 = (const float4*)(emb + (size_t)kb * DIM);
  float4 zv0 = zr4[l * 2], zv1 = zr4[l * 2 + 1];
  float4 qv0 = qr4[l * 2], qv1 = qr4[l * 2 + 1];
  float ls = 0.f; float4 ov0, ov1;
  {
    const float* zp=(const float*)&zv0; const float* qp=(const float*)&qv0; float* op=(float*)&ov0;
    #pragma unroll
    for (int e = 0; e < 4; ++e) { float d = qp[e]-zp[e]; op[e] = zp[e]+d; ls += d*d; }
  }
  {
    const float* zp=(const float*)&zv1; const float* qp=(const float*)&qv1; float* op=(float*)&ov1;
    #pragma unroll
    for (int e = 0; e < 4; ++e) { float d = qp[e]-zp[e]; op[e] = zp[e]+d; ls += d*d; }
  }
  float4* orow = (float4*)(out + (size_t)row * DIM);
  orow[l * 2] = ov0; orow[l * 2 + 1] = ov1;
  #pragma unroll
  for (int m = 32; m >= 1; m >>= 1) ls += __shfl_xor(ls, m);
  if (l == 0) {
    out[(size_t)N_TOK * DIM + 1 + row] = (float)kb;
    atomicAdd(acc, (double)ls);
  }
}

__global__ void vq_loss(const double* __restrict__ acc, float* __restrict__ out) {
  out[(size_t)N_TOK * DIM] =
      (float)(*acc * (1.0 + (double)BETA) / ((double)N_TOK * (double)DIM));
}

extern "C" void kernel_launch(void* const* d_in, const int* in_sizes, int n_in,
                              void* d_out, int out_size, void* d_ws, size_t ws_size,
                              hipStream_t stream) {
  const float* z   = (const float*)d_in[0];
  const float* emb = (const float*)d_in[1];
  float* out = (float*)d_out;
  char* ws = (char*)d_ws;
  double* acc  = (double*)(ws + WS_ACC);
  int*    cnt  = (int*)(ws + WS_CNT);
  float*  pmax = (float*)(ws + WS_PMAX);
  int*    pidx = (int*)(ws + WS_PIDX);
  int*    extk = (int*)(ws + WS_EXTK);
  float*  s1   = (float*)(ws + WS_S1);
  short*  zh   = (short*)(ws + WS_ZH);
  short*  eh   = (short*)(ws + WS_EH);

  hipMemsetAsync(ws, 0, WS_CNT + (size_t)N_TOK * NKT * 4, stream);  // acc + cnt
  vq_pack_z<<<N_TOK / 4, 256, 0, stream>>>(z, zh, s1);
  vq_pack_e<<<NEMB / 4, 256, 0, stream>>>(emb, eh);
  vq_mfma<<<dim3(NEMB / 256, N_TOK / 256), 512, 0, stream>>>(zh, eh, pmax, pidx, cnt, extk);
  vq_finalize<<<N_TOK / 4, 256, 0, stream>>>(z, emb, s1, pmax, pidx, cnt, extk, out, acc);
  vq_loss<<<1, 1, 0, stream>>>(acc, out);
}